// Round 1
// baseline (1526.289 us; speedup 1.0000x reference)
//
#include <hip/hip_runtime.h>

#define N_NODES 50000
#define N_EDGES 600000
#define HID 128
#define N_LAYERS 3
#define N_GRAPHS 64

// ---------------- h = x * node_imp ----------------
__global__ __launch_bounds__(256) void scale_kernel(const float* __restrict__ x,
                                                    const float* __restrict__ imp,
                                                    float* __restrict__ h) {
  int i = blockIdx.x * 256 + threadIdx.x;            // over N_NODES*32 float4
  if (i >= N_NODES * (HID / 4)) return;
  float s = imp[i >> 5];
  float4 v = reinterpret_cast<const float4*>(x)[i];
  v.x *= s; v.y *= s; v.z *= s; v.w *= s;
  reinterpret_cast<float4*>(h)[i] = v;
}

// ---------------- CSR build: histogram ----------------
__global__ __launch_bounds__(256) void hist_kernel(const int* __restrict__ dst,
                                                   int* __restrict__ deg) {
  int e = blockIdx.x * 256 + threadIdx.x;
  if (e < N_EDGES) atomicAdd(&deg[dst[e]], 1);
}

// ---------------- CSR build: exclusive scan (single block, 1024 thr) --------
// rowptr[0..N_NODES] = exclusive prefix sum of deg; cursor[i] = rowptr[i]
__global__ __launch_bounds__(1024) void scan_kernel(const int* __restrict__ deg,
                                                    int* __restrict__ rowptr,
                                                    int* __restrict__ cursor) {
  __shared__ int temp[1024];
  __shared__ int carry_sh;
  int tid = threadIdx.x;
  if (tid == 0) { carry_sh = 0; rowptr[0] = 0; }
  __syncthreads();
  for (int base = 0; base < N_NODES; base += 1024) {
    int i = base + tid;
    int v = (i < N_NODES) ? deg[i] : 0;
    temp[tid] = v;
    __syncthreads();
    // Hillis-Steele inclusive scan
    for (int off = 1; off < 1024; off <<= 1) {
      int t = (tid >= off) ? temp[tid - off] : 0;
      __syncthreads();
      temp[tid] += t;
      __syncthreads();
    }
    int carry = carry_sh;
    if (i < N_NODES) {
      rowptr[i + 1] = carry + temp[tid];       // inclusive -> rowptr[i+1]
      cursor[i]     = carry + temp[tid] - v;   // exclusive -> cursor/rowptr[i]
    }
    __syncthreads();
    if (tid == 1023) carry_sh = carry + temp[1023];
    __syncthreads();
  }
}

// ---------------- CSR build: scatter edge sources by dst ----------------
__global__ __launch_bounds__(256) void scatter_kernel(const int* __restrict__ src,
                                                      const int* __restrict__ dst,
                                                      int* __restrict__ cursor,
                                                      int* __restrict__ esrc) {
  int e = blockIdx.x * 256 + threadIdx.x;
  if (e >= N_EDGES) return;
  int pos = atomicAdd(&cursor[dst[e]], 1);
  esrc[pos] = src[e];
}

// ---------------- z = h + sum_{j->i} h[j]  (one wave per node) --------------
__global__ __launch_bounds__(256) void aggr_kernel(const float* __restrict__ h,
                                                   const int* __restrict__ rowptr,
                                                   const int* __restrict__ esrc,
                                                   float* __restrict__ z) {
  int wid = (blockIdx.x * 256 + threadIdx.x) >> 6;   // node id, 1 wave each
  if (wid >= N_NODES) return;
  int lane = threadIdx.x & 63;
  const float2* h2 = reinterpret_cast<const float2*>(h);
  float2 acc = h2[(size_t)wid * 64 + lane];          // self term (eps = 0)
  int s = rowptr[wid], e = rowptr[wid + 1];
  for (int j = s; j < e; ++j) {
    int sn = esrc[j];                                // uniform across wave
    float2 v = h2[(size_t)sn * 64 + lane];           // coalesced 512B row
    acc.x += v.x; acc.y += v.y;
  }
  reinterpret_cast<float2*>(z)[(size_t)wid * 64 + lane] = acc;
}

// ---------------- fused MLP + h-update + pool ----------------
// h = relu( relu(z@W1+b1)@W2 + b2 ) * imp ; out[batch[i], lofs:lofs+128] += h
// 256 thr: thread = (rg 0..7) x (fg 0..31); 4 rows x 4 cols per thread.
// LDS: W1 64KB + W2 64KB + 32-row z tile 16KB = 144KB -> 1 block/CU.
__global__ __launch_bounds__(256) void mlp_pool_kernel(
    const float* __restrict__ z, const float* __restrict__ W1,
    const float* __restrict__ b1, const float* __restrict__ W2,
    const float* __restrict__ b2, const float* __restrict__ imp,
    const int* __restrict__ batch, float* __restrict__ h,
    float* __restrict__ out, int lofs) {
  __shared__ float W1s[HID * HID];
  __shared__ float W2s[HID * HID];
  __shared__ float zs[32 * HID];                     // reused as t-buffer

  const int tid = threadIdx.x;
  {
    const float4* a = reinterpret_cast<const float4*>(W1);
    const float4* b = reinterpret_cast<const float4*>(W2);
    float4* sa = reinterpret_cast<float4*>(W1s);
    float4* sb = reinterpret_cast<float4*>(W2s);
#pragma unroll
    for (int i = 0; i < 16; ++i) {
      sa[tid + i * 256] = a[tid + i * 256];
      sb[tid + i * 256] = b[tid + i * 256];
    }
  }
  const int fg = tid & 31;                           // cols fg*4 .. fg*4+3
  const int rg = tid >> 5;                           // rows rg*4 .. rg*4+3
  const float4 bias1 = reinterpret_cast<const float4*>(b1)[fg];
  const float4 bias2 = reinterpret_cast<const float4*>(b2)[fg];
  __syncthreads();

  const int nchunks = (N_NODES + 31) >> 5;
  for (int c = blockIdx.x; c < nchunks; c += gridDim.x) {
    const int row0 = c << 5;
    {  // stage 32 rows of z
      const float4* zv = reinterpret_cast<const float4*>(z);
      float4* zsv = reinterpret_cast<float4*>(zs);
#pragma unroll
      for (int i = 0; i < 4; ++i) {
        int idx = tid + i * 256;
        int rr = row0 + (idx >> 5);
        zsv[idx] = (rr < N_NODES) ? zv[(size_t)rr * 32 + (idx & 31)]
                                  : make_float4(0.f, 0.f, 0.f, 0.f);
      }
    }
    __syncthreads();

    // ---- GEMM1: a_ = z @ W1 + b1 ----
    float a_[4][4];
#pragma unroll
    for (int r = 0; r < 4; ++r) {
      a_[r][0] = bias1.x; a_[r][1] = bias1.y; a_[r][2] = bias1.z; a_[r][3] = bias1.w;
    }
    {
      const float4* Wv = reinterpret_cast<const float4*>(W1s);
      const float4* zv4 = reinterpret_cast<const float4*>(zs);
#pragma unroll 4
      for (int k4 = 0; k4 < 32; ++k4) {
        float4 w0 = Wv[(4 * k4 + 0) * 32 + fg];
        float4 w1 = Wv[(4 * k4 + 1) * 32 + fg];
        float4 w2 = Wv[(4 * k4 + 2) * 32 + fg];
        float4 w3 = Wv[(4 * k4 + 3) * 32 + fg];
#pragma unroll
        for (int r = 0; r < 4; ++r) {
          float4 zq = zv4[(rg * 4 + r) * 32 + k4];
          a_[r][0] += zq.x * w0.x + zq.y * w1.x + zq.z * w2.x + zq.w * w3.x;
          a_[r][1] += zq.x * w0.y + zq.y * w1.y + zq.z * w2.y + zq.w * w3.y;
          a_[r][2] += zq.x * w0.z + zq.y * w1.z + zq.z * w2.z + zq.w * w3.z;
          a_[r][3] += zq.x * w0.w + zq.y * w1.w + zq.z * w2.w + zq.w * w3.w;
        }
      }
    }
    __syncthreads();  // all zs reads done; safe to overwrite with t

    // ---- t = relu(a_) into zs ----
#pragma unroll
    for (int r = 0; r < 4; ++r) {
      float4 t;
      t.x = fmaxf(a_[r][0], 0.f); t.y = fmaxf(a_[r][1], 0.f);
      t.z = fmaxf(a_[r][2], 0.f); t.w = fmaxf(a_[r][3], 0.f);
      reinterpret_cast<float4*>(zs)[(rg * 4 + r) * 32 + fg] = t;
    }
    __syncthreads();

    // ---- GEMM2: o_ = t @ W2 + b2 ----
    float o_[4][4];
#pragma unroll
    for (int r = 0; r < 4; ++r) {
      o_[r][0] = bias2.x; o_[r][1] = bias2.y; o_[r][2] = bias2.z; o_[r][3] = bias2.w;
    }
    {
      const float4* Wv = reinterpret_cast<const float4*>(W2s);
      const float4* tv4 = reinterpret_cast<const float4*>(zs);
#pragma unroll 4
      for (int k4 = 0; k4 < 32; ++k4) {
        float4 w0 = Wv[(4 * k4 + 0) * 32 + fg];
        float4 w1 = Wv[(4 * k4 + 1) * 32 + fg];
        float4 w2 = Wv[(4 * k4 + 2) * 32 + fg];
        float4 w3 = Wv[(4 * k4 + 3) * 32 + fg];
#pragma unroll
        for (int r = 0; r < 4; ++r) {
          float4 tq = tv4[(rg * 4 + r) * 32 + k4];
          o_[r][0] += tq.x * w0.x + tq.y * w1.x + tq.z * w2.x + tq.w * w3.x;
          o_[r][1] += tq.x * w0.y + tq.y * w1.y + tq.z * w2.y + tq.w * w3.y;
          o_[r][2] += tq.x * w0.z + tq.y * w1.z + tq.z * w2.z + tq.w * w3.z;
          o_[r][3] += tq.x * w0.w + tq.y * w1.w + tq.z * w2.w + tq.w * w3.w;
        }
      }
    }

    // ---- epilogue: h = relu(o_)*imp, write h, pool into out ----
#pragma unroll
    for (int r = 0; r < 4; ++r) {
      int row = row0 + rg * 4 + r;
      if (row < N_NODES) {
        float s = imp[row];
        float4 hv;
        hv.x = fmaxf(o_[r][0], 0.f) * s; hv.y = fmaxf(o_[r][1], 0.f) * s;
        hv.z = fmaxf(o_[r][2], 0.f) * s; hv.w = fmaxf(o_[r][3], 0.f) * s;
        reinterpret_cast<float4*>(h)[(size_t)row * 32 + fg] = hv;
        float* op = out + batch[row] * (N_LAYERS * HID) + lofs + fg * 4;
        atomicAdd(op + 0, hv.x); atomicAdd(op + 1, hv.y);
        atomicAdd(op + 2, hv.z); atomicAdd(op + 3, hv.w);
      }
    }
    __syncthreads();  // before next chunk overwrites zs
  }
}

extern "C" void kernel_launch(void* const* d_in, const int* in_sizes, int n_in,
                              void* d_out, int out_size, void* d_ws, size_t ws_size,
                              hipStream_t stream) {
  const float* x    = (const float*)d_in[0];
  const int*   ei   = (const int*)d_in[1];          // [2, N_EDGES]
  const int*   batch= (const int*)d_in[2];
  const float* imp  = (const float*)d_in[3];
  const float* W1   = (const float*)d_in[4];        // [3,128,128]
  const float* b1   = (const float*)d_in[5];        // [3,128]
  const float* W2   = (const float*)d_in[6];
  const float* b2   = (const float*)d_in[7];
  float* out = (float*)d_out;                       // [64, 384]

  const int* src = ei;
  const int* dst = ei + N_EDGES;

  // workspace layout (16B-aligned floats first)
  char* w = (char*)d_ws;
  float* h = (float*)w;        w += (size_t)N_NODES * HID * sizeof(float);   // 25.6MB
  float* z = (float*)w;        w += (size_t)N_NODES * HID * sizeof(float);   // 25.6MB
  int* esrc   = (int*)w;       w += (size_t)N_EDGES * sizeof(int);           // 2.4MB
  int* deg    = (int*)w;       w += (size_t)N_NODES * sizeof(int);
  int* cursor = (int*)w;       w += (size_t)N_NODES * sizeof(int);
  int* rowptr = (int*)w;       w += ((size_t)N_NODES + 1) * sizeof(int);

  hipMemsetAsync(out, 0, (size_t)N_GRAPHS * N_LAYERS * HID * sizeof(float), stream);
  hipMemsetAsync(deg, 0, (size_t)N_NODES * sizeof(int), stream);

  scale_kernel<<<(N_NODES * 32 + 255) / 256, 256, 0, stream>>>(x, imp, h);
  hist_kernel<<<(N_EDGES + 255) / 256, 256, 0, stream>>>(dst, deg);
  scan_kernel<<<1, 1024, 0, stream>>>(deg, rowptr, cursor);
  scatter_kernel<<<(N_EDGES + 255) / 256, 256, 0, stream>>>(src, dst, cursor, esrc);

  for (int l = 0; l < N_LAYERS; ++l) {
    aggr_kernel<<<(N_NODES + 3) / 4, 256, 0, stream>>>(h, rowptr, esrc, z);
    mlp_pool_kernel<<<256, 256, 0, stream>>>(
        z, W1 + (size_t)l * HID * HID, b1 + (size_t)l * HID,
        W2 + (size_t)l * HID * HID, b2 + (size_t)l * HID,
        imp, batch, h, out, l * HID);
  }
}